// Round 3
// baseline (1560.797 us; speedup 1.0000x reference)
//
#include <hip/hip_runtime.h>
#include <hip/hip_bf16.h>
#include <cstdint>

#define T_ 512
#define B_ 1024
#define D_ 6
#define H_ 128

typedef _Float16 f16;
typedef _Float16 f16x8 __attribute__((ext_vector_type(8)));
typedef float f32x4 __attribute__((ext_vector_type(4)));

// branch-free erf (Abramowitz-Stegun 7.1.26, max abs err 1.5e-7)
__device__ __forceinline__ float erf_f(float x) {
    float ax = fabsf(x);
    float t = __builtin_amdgcn_rcpf(fmaf(0.3275911f, ax, 1.f));
    float p = fmaf(t, 1.061405429f, -1.453152027f);
    p = fmaf(t, p, 1.421413741f);
    p = fmaf(t, p, -0.284496736f);
    p = fmaf(t, p, 0.254829592f);
    p = p * t;
    float e = __builtin_amdgcn_exp2f(-ax * ax * 1.4426950408889634f);
    float r = 1.f - p * e;
    return copysignf(r, x);
}
__device__ __forceinline__ float gelu_f(float x) {
    return 0.5f * x * (1.f + erf_f(x * 0.7071067811865476f));
}
__device__ __forceinline__ float sig_f(float x) {
    return __builtin_amdgcn_rcpf(1.f + __builtin_amdgcn_exp2f(-1.4426950408889634f * x));
}
__device__ __forceinline__ float tanh_f(float x) {
    return 2.f * sig_f(2.f * x) - 1.f;
}
__device__ __forceinline__ f16x8 load8cvt(const float* p) {
    float4 a = ((const float4*)p)[0];
    float4 b = ((const float4*)p)[1];
    f16x8 r = { (f16)a.x, (f16)a.y, (f16)a.z, (f16)a.w,
                (f16)b.x, (f16)b.y, (f16)b.z, (f16)b.w };
    return r;
}
// LDS tiles: row-major [rows][128] f16, 256B row stride, 16B-chunk XOR swizzle
__device__ __forceinline__ f16x8 lds_rd8(const f16* base, int row, int cb) {
    const char* p = (const char*)base + row * 256 + (cb ^ ((row & 7) << 4));
    return *(const f16x8*)p;
}
__device__ __forceinline__ void lds_wr8(f16* base, int row, int cb, f16x8 v) {
    char* p = (char*)base + row * 256 + (cb ^ ((row & 7) << 4));
    *(f16x8*)p = v;
}
__device__ __forceinline__ void lds_wr1(f16* base, int row, int col, f16 v) {
    char* p = (char*)base + row * 256 + ((col * 2) ^ ((row & 7) << 4));
    *(f16*)p = v;
}

// ---------------------------------------------------------------------------
// K1: fused conv stack (4 pointwise layers + GELU) + pos_embed -> x (T,B,H) f16
// grid: 1024 = (64 t-groups of 8) x (16 batch groups of 64 rows); 256 threads.
// Weight fragments loaded once per block, reused across 8 timesteps.
// Final tile staged in LDS, then flushed with coalesced f16x8 stores
// (scalar f16 global stores caused 1.2GB RMW fetch + 3.4x write amplification).
// ---------------------------------------------------------------------------
__global__ __launch_bounds__(256, 2) void conv_stack_k(
    const float* __restrict__ src,
    const float* __restrict__ w0p, const float* __restrict__ b0p,
    const float* __restrict__ w1p, const float* __restrict__ b1p,
    const float* __restrict__ w2p, const float* __restrict__ b2p,
    const float* __restrict__ w3p, const float* __restrict__ b3p,
    const float* __restrict__ posp, f16* __restrict__ xb)
{
    __shared__ f16 A0[64 * 128];
    __shared__ f16 A1[64 * 128];
    const int tid = threadIdx.x;
    const int lane = tid & 63, wid = tid >> 6;
    const int l16 = lane & 15, hi = lane >> 4;
    const int t0 = (blockIdx.x & 63) * 8;
    const int bb0 = (blockIdx.x >> 6) * 64;

    // weight fragments for layers 1..3 (loaded once per block)
    f16x8 wfr[3][2][4];
    float bias[3][2];
    const float* wp[3] = { w1p, w2p, w3p };
    const float* bp[3] = { b1p, b2p, b3p };
#pragma unroll
    for (int L = 0; L < 3; ++L) {
#pragma unroll
        for (int ni = 0; ni < 2; ++ni) {
            int col = wid * 32 + ni * 16 + l16;
            bias[L][ni] = bp[L][col];
#pragma unroll
            for (int ki = 0; ki < 4; ++ki)
                wfr[L][ni][ki] = load8cvt(wp[L] + col * 128 + ki * 32 + hi * 8);
        }
    }

    for (int it = 0; it < 8; ++it) {
        const int t = t0 + it;
        __syncthreads();  // prior iter's A0/A1 readers done
        // layer 0: D=6 -> H=128, plain VALU; 4 threads per row, 32 cols each
        {
            const int r = tid >> 2, cs = tid & 3;
            const float2* sp = (const float2*)src + ((size_t)(bb0 + r) * T_ + t) * 3;
            float2 s01 = sp[0], s23 = sp[1], s45 = sp[2];
            float sv[6] = { s01.x, s01.y, s23.x, s23.y, s45.x, s45.y };
#pragma unroll
            for (int i = 0; i < 4; ++i) {
                f16x8 v;
#pragma unroll
                for (int j = 0; j < 8; ++j) {
                    int n = cs * 32 + i * 8 + j;
                    float a = b0p[n];
#pragma unroll
                    for (int k = 0; k < 6; ++k) a = fmaf(sv[k], w0p[n * 6 + k], a);
                    v[j] = (f16)gelu_f(a);
                }
                lds_wr8(A0, r, cs * 64 + i * 16, v);
            }
        }

        f16* bufs[2] = { A0, A1 };
#pragma unroll
        for (int L = 0; L < 3; ++L) {
            __syncthreads();
            f16* Ain = bufs[L & 1];
            f32x4 acc[4][2];
#pragma unroll
            for (int mi = 0; mi < 4; ++mi)
#pragma unroll
                for (int ni = 0; ni < 2; ++ni) {
                    f32x4 bv = { bias[L][ni], bias[L][ni], bias[L][ni], bias[L][ni] };
                    acc[mi][ni] = bv;
                }
#pragma unroll
            for (int ki = 0; ki < 4; ++ki) {
                f16x8 af[4];
#pragma unroll
                for (int mi = 0; mi < 4; ++mi)
                    af[mi] = lds_rd8(Ain, mi * 16 + l16, ki * 64 + hi * 16);
#pragma unroll
                for (int mi = 0; mi < 4; ++mi)
#pragma unroll
                    for (int ni = 0; ni < 2; ++ni)
                        acc[mi][ni] = __builtin_amdgcn_mfma_f32_16x16x32_f16(
                            af[mi], wfr[L][ni][ki], acc[mi][ni], 0, 0, 0);
            }
            if (L < 2) {
                f16* Aout = bufs[(L + 1) & 1];
#pragma unroll
                for (int mi = 0; mi < 4; ++mi)
#pragma unroll
                    for (int ni = 0; ni < 2; ++ni) {
                        int col = wid * 32 + ni * 16 + l16;
#pragma unroll
                        for (int j = 0; j < 4; ++j) {
                            int row = mi * 16 + hi * 4 + j;
                            lds_wr1(Aout, row, col, (f16)gelu_f(acc[mi][ni][j]));
                        }
                    }
            } else {
                // stage final tile (gelu + pos) into A1
#pragma unroll
                for (int mi = 0; mi < 4; ++mi)
#pragma unroll
                    for (int ni = 0; ni < 2; ++ni) {
                        int col = wid * 32 + ni * 16 + l16;
                        float pv = posp[t * 128 + col];
#pragma unroll
                        for (int j = 0; j < 4; ++j) {
                            int row = mi * 16 + hi * 4 + j;
                            lds_wr1(A1, row, col, (f16)(gelu_f(acc[mi][ni][j]) + pv));
                        }
                    }
            }
        }
        __syncthreads();
        // coalesced flush: 64 rows x 256B; lane-consecutive 16B chunks
        f16* xrow = xb + (size_t)t * (B_ * H_) + (size_t)bb0 * H_;
#pragma unroll
        for (int c = tid, k = 0; k < 4; ++k, c += 256) {
            int row = c >> 4, cw = c & 15;
            f16x8 v = lds_rd8(A1, row, cw * 16);
            *(f16x8*)(xrow + (size_t)row * H_ + cw * 8) = v;
        }
    }
}

// ---------------------------------------------------------------------------
// K2/K3: one LSTM layer. 256 blocks x 512 threads (8 waves), 4 batch rows per
// block mapped to MFMA rows {0,4,8,12} so every lane's acc[g][0] is a real
// gate value: fully in-register pointwise, no Z round-trip. Wave w owns hid
// columns [16w,16w+16) for ALL four gates (n = g*128 + 16w + l16).
// h double-buffered in swizzled LDS (one barrier/step); c,h fp32 in regs;
// x[t+1] prefetched into registers during step t.
// ---------------------------------------------------------------------------
template <bool WRITE_YS, bool WRITE_H>
__global__ __launch_bounds__(512, 2) void lstm_k(
    const f16* xb,
    const float* __restrict__ Wih, const float* __restrict__ Whh,
    const float* __restrict__ bih, const float* __restrict__ bhh,
    f16* ys, float* __restrict__ hfin)
{
    __shared__ f16 HL[2][16 * 128];
    const int tid = threadIdx.x;
    const int lane = tid & 63, wid = tid >> 6;
    const int l16 = lane & 15, hi = lane >> 4;
    const int bb0 = blockIdx.x * 4;

    f16x8 wih[4][4], whh[4][4];
    float bias[4];
#pragma unroll
    for (int g = 0; g < 4; ++g) {
        int n = g * 128 + wid * 16 + l16;
        bias[g] = bih[n] + bhh[n];
#pragma unroll
        for (int ki = 0; ki < 4; ++ki) {
            wih[g][ki] = load8cvt(Wih + n * 128 + ki * 32 + hi * 8);
            whh[g][ki] = load8cvt(Whh + n * 128 + ki * 32 + hi * 8);
        }
    }
    for (int i = tid; i < 2 * 16 * 128; i += 512) ((f16*)HL)[i] = (f16)0.f;

    const bool arow = (l16 & 3) == 0;     // A-fragment rows {0,4,8,12} are real
    const int brow = l16 >> 2;            // batch row within block (A side)
    const f16* xbase = xb + (size_t)(bb0 + brow) * H_;
    const int mycol = wid * 16 + l16;     // this lane's hid column (C side)
    float c = 0.f, h = 0.f;
    __syncthreads();

    f16x8 xa[4];
    const f16x8 zero8 = { 0, 0, 0, 0, 0, 0, 0, 0 };
#pragma unroll
    for (int ki = 0; ki < 4; ++ki)
        xa[ki] = arow ? *(const f16x8*)(xbase + ki * 32 + hi * 8) : zero8;

    for (int t = 0; t < T_; ++t) {
        // prefetch next timestep's x into registers (t=511's prefetch unused)
        const int tn = (t + 1 < T_) ? t + 1 : T_ - 1;
        const f16* xnp = xbase + (size_t)tn * (B_ * H_);
        f16x8 xn[4];
#pragma unroll
        for (int ki = 0; ki < 4; ++ki)
            xn[ki] = arow ? *(const f16x8*)(xnp + ki * 32 + hi * 8) : zero8;

        f16x8 ha[4];
#pragma unroll
        for (int ki = 0; ki < 4; ++ki)
            ha[ki] = lds_rd8(HL[t & 1], l16, ki * 64 + hi * 16);

        f32x4 acc[4];
#pragma unroll
        for (int g = 0; g < 4; ++g) {
            f32x4 bv = { bias[g], bias[g], bias[g], bias[g] };
            acc[g] = bv;
        }
#pragma unroll
        for (int ki = 0; ki < 4; ++ki)
#pragma unroll
            for (int g = 0; g < 4; ++g)
                acc[g] = __builtin_amdgcn_mfma_f32_16x16x32_f16(xa[ki], wih[g][ki], acc[g], 0, 0, 0);
#pragma unroll
        for (int ki = 0; ki < 4; ++ki)
#pragma unroll
            for (int g = 0; g < 4; ++g)
                acc[g] = __builtin_amdgcn_mfma_f32_16x16x32_f16(ha[ki], whh[g][ki], acc[g], 0, 0, 0);

        // every lane: real gate quadruple at j=0 for (row=hi, col=mycol)
        float zi = acc[0][0], zf = acc[1][0], zg = acc[2][0], zo = acc[3][0];
        c = sig_f(zf) * c + sig_f(zi) * tanh_f(zg);
        h = sig_f(zo) * tanh_f(c);
        lds_wr1(HL[(t + 1) & 1], hi * 4, mycol, (f16)h);
        if (WRITE_YS)
            ys[(size_t)t * (B_ * H_) + (size_t)(bb0 + hi) * H_ + mycol] = (f16)h;

#pragma unroll
        for (int ki = 0; ki < 4; ++ki) xa[ki] = xn[ki];
        __syncthreads();
    }
    if (WRITE_H)
        hfin[(size_t)(bb0 + hi) * H_ + mycol] = h;
}

// ---------------------------------------------------------------------------
// K4: head — LayerNorm + Linear(128->32) + GELU + Linear(32->8). 4 rows/block.
// ---------------------------------------------------------------------------
__global__ __launch_bounds__(256) void head_k(
    const float* __restrict__ hfin,
    const float* __restrict__ lng, const float* __restrict__ lnb,
    const float* __restrict__ hw1, const float* __restrict__ hb1,
    const float* __restrict__ hw2, const float* __restrict__ hb2,
    float* __restrict__ outp)
{
    __shared__ float HN[4][128];
    __shared__ float G[4][32];
    const int tid = threadIdx.x, lane = tid & 63, wid = tid >> 6;
    const int b = blockIdx.x * 4 + wid;
    float v0 = hfin[b * 128 + lane], v1 = hfin[b * 128 + 64 + lane];
    float s = v0 + v1;
#pragma unroll
    for (int m = 1; m < 64; m <<= 1) s += __shfl_xor(s, m);
    float mu = s * (1.f / 128.f);
    float d0 = v0 - mu, d1 = v1 - mu;
    float q = d0 * d0 + d1 * d1;
#pragma unroll
    for (int m = 1; m < 64; m <<= 1) q += __shfl_xor(q, m);
    float rs = rsqrtf(q * (1.f / 128.f) + 1e-5f);
    HN[wid][lane] = d0 * rs * lng[lane] + lnb[lane];
    HN[wid][64 + lane] = d1 * rs * lng[64 + lane] + lnb[64 + lane];
    __syncthreads();
    if (tid < 128) {
        int row = tid >> 5, o = tid & 31;
        float a = hb1[o];
#pragma unroll 4
        for (int k = 0; k < 128; ++k) a = fmaf(HN[row][k], hw1[o * 128 + k], a);
        G[row][o] = gelu_f(a);
    }
    __syncthreads();
    if (tid < 32) {
        int row = tid >> 3, oo = tid & 7;
        float a = hb2[oo];
#pragma unroll
        for (int k = 0; k < 32; ++k) a = fmaf(G[row][k], hw2[oo * 32 + k], a);
        outp[(size_t)(blockIdx.x * 4 + row) * 8 + oo] = a;
    }
}

extern "C" void kernel_launch(void* const* d_in, const int* in_sizes, int n_in,
                              void* d_out, int out_size, void* d_ws, size_t ws_size,
                              hipStream_t stream) {
    (void)in_sizes; (void)n_in; (void)out_size; (void)ws_size;
    const float* src  = (const float*)d_in[0];
    const float* w0   = (const float*)d_in[1];
    const float* b0   = (const float*)d_in[2];
    const float* w1   = (const float*)d_in[3];
    const float* b1   = (const float*)d_in[4];
    const float* w2   = (const float*)d_in[5];
    const float* b2   = (const float*)d_in[6];
    const float* w3   = (const float*)d_in[7];
    const float* b3   = (const float*)d_in[8];
    const float* pos  = (const float*)d_in[9];
    const float* Wih0 = (const float*)d_in[10];
    const float* Whh0 = (const float*)d_in[11];
    const float* bih0 = (const float*)d_in[12];
    const float* bhh0 = (const float*)d_in[13];
    const float* Wih1 = (const float*)d_in[14];
    const float* Whh1 = (const float*)d_in[15];
    const float* bih1 = (const float*)d_in[16];
    const float* bhh1 = (const float*)d_in[17];
    const float* lng  = (const float*)d_in[18];
    const float* lnb  = (const float*)d_in[19];
    const float* hw1  = (const float*)d_in[20];
    const float* hb1  = (const float*)d_in[21];
    const float* hw2  = (const float*)d_in[22];
    const float* hb2  = (const float*)d_in[23];
    float* outp = (float*)d_out;

    f16* xbuf = (f16*)d_ws;                                  // (T,B,H) f16 = 128 MB
    float* hfin = (float*)((char*)d_ws + (size_t)134217728); // (B,H) f32

    conv_stack_k<<<dim3(1024), dim3(256), 0, stream>>>(
        src, w0, b0, w1, b1, w2, b2, w3, b3, pos, xbuf);
    lstm_k<true, false><<<dim3(256), dim3(512), 0, stream>>>(
        xbuf, Wih0, Whh0, bih0, bhh0, xbuf, nullptr);
    lstm_k<false, true><<<dim3(256), dim3(512), 0, stream>>>(
        xbuf, Wih1, Whh1, bih1, bhh1, nullptr, hfin);
    head_k<<<dim3(256), dim3(256), 0, stream>>>(
        hfin, lng, lnb, hw1, hb1, hw2, hb2, outp);
}

// Round 4
// 1319.309 us; speedup vs baseline: 1.1830x; 1.1830x over previous
//
#include <hip/hip_runtime.h>
#include <hip/hip_bf16.h>
#include <cstdint>

#define T_ 512
#define B_ 1024
#define D_ 6
#define H_ 128

typedef _Float16 f16;
typedef _Float16 f16x8 __attribute__((ext_vector_type(8)));
typedef float f32x4 __attribute__((ext_vector_type(4)));

// branch-free erf (Abramowitz-Stegun 7.1.26, max abs err 1.5e-7)
__device__ __forceinline__ float erf_f(float x) {
    float ax = fabsf(x);
    float t = __builtin_amdgcn_rcpf(fmaf(0.3275911f, ax, 1.f));
    float p = fmaf(t, 1.061405429f, -1.453152027f);
    p = fmaf(t, p, 1.421413741f);
    p = fmaf(t, p, -0.284496736f);
    p = fmaf(t, p, 0.254829592f);
    p = p * t;
    float e = __builtin_amdgcn_exp2f(-ax * ax * 1.4426950408889634f);
    float r = 1.f - p * e;
    return copysignf(r, x);
}
__device__ __forceinline__ float gelu_f(float x) {
    return 0.5f * x * (1.f + erf_f(x * 0.7071067811865476f));
}
__device__ __forceinline__ float sig_f(float x) {
    return __builtin_amdgcn_rcpf(1.f + __builtin_amdgcn_exp2f(-1.4426950408889634f * x));
}
__device__ __forceinline__ float tanh_f(float x) {
    return 2.f * sig_f(2.f * x) - 1.f;
}
__device__ __forceinline__ f16x8 load8cvt(const float* p) {
    float4 a = ((const float4*)p)[0];
    float4 b = ((const float4*)p)[1];
    f16x8 r = { (f16)a.x, (f16)a.y, (f16)a.z, (f16)a.w,
                (f16)b.x, (f16)b.y, (f16)b.z, (f16)b.w };
    return r;
}
// LDS tiles: row-major [rows][128] f16, 256B row stride, 16B-chunk XOR swizzle
__device__ __forceinline__ f16x8 lds_rd8(const f16* base, int row, int cb) {
    const char* p = (const char*)base + row * 256 + (cb ^ ((row & 7) << 4));
    return *(const f16x8*)p;
}
__device__ __forceinline__ void lds_wr1(f16* base, int row, int col, f16 v) {
    char* p = (char*)base + row * 256 + ((col * 2) ^ ((row & 7) << 4));
    *(f16*)p = v;
}

// ---------------------------------------------------------------------------
// K1: FUSED conv stack + LSTM layer 0. 256 blocks x 512 threads (8 waves),
// 4 batch rows per block. Per step t:
//   P0: conv layer0 (D=6->128, VALU, 1 output/thread) -> XA; wave0 flushes
//       ys[t-1] (coalesced 1KB); prefetch src(t+1), pos(t).
//   P1-P3: conv layers 1..3 as M=16(4 real)x N=16/wave x K=128 MFMA,
//          B-frags from LDS (CW, 96KB); ping-pong XA/XB; L3 adds pos_embed.
//   P4: lstm0 gates: 32 MFMA (x-side from XB, h-side from HL dbuf);
//       in-register pointwise (every lane's acc[g][0] is real: row=hi,
//       col=wid*16+l16); h -> HL[(t+1)&1].
// Conv weights in LDS keeps regs ~210/wave -> 2 waves/SIMD (vs 1 before).
// x never touches global memory; ys written once (read by lstm1).
// ---------------------------------------------------------------------------
__global__ __launch_bounds__(512, 2) void fused_conv_lstm0_k(
    const float* __restrict__ src,
    const float* __restrict__ w0p, const float* __restrict__ b0p,
    const float* __restrict__ w1p, const float* __restrict__ b1p,
    const float* __restrict__ w2p, const float* __restrict__ b2p,
    const float* __restrict__ w3p, const float* __restrict__ b3p,
    const float* __restrict__ posp,
    const float* __restrict__ Wih, const float* __restrict__ Whh,
    const float* __restrict__ bih, const float* __restrict__ bhh,
    f16* __restrict__ ys)
{
    __shared__ f16 CW[3 * 8 * 4 * 512];   // 96KB: conv w1..w3 B-fragments
    __shared__ f16 XA[16 * 128];          // 4KB activation ping
    __shared__ f16 XB[16 * 128];          // 4KB activation pong
    __shared__ f16 HL[2][16 * 128];       // 8KB h double-buffer
    const int tid = threadIdx.x;
    const int lane = tid & 63, wid = tid >> 6;
    const int l16 = lane & 15, hi = lane >> 4;
    const int bb0 = blockIdx.x * 4;
    const int mycol = wid * 16 + l16;

    // lstm0 weight fragments in registers (wave owns 16 cols of all 4 gates)
    f16x8 wih[4][4], whh[4][4];
    float biasg[4];
#pragma unroll
    for (int g = 0; g < 4; ++g) {
        int n = g * 128 + mycol;
        biasg[g] = bih[n] + bhh[n];
#pragma unroll
        for (int ki = 0; ki < 4; ++ki) {
            wih[g][ki] = load8cvt(Wih + n * 128 + ki * 32 + hi * 8);
            whh[g][ki] = load8cvt(Whh + n * 128 + ki * 32 + hi * 8);
        }
    }

    // conv layer0 per-thread slice + conv biases
    const int col0 = tid & 127;   // L0 output col
    const int row0 = tid >> 7;    // L0 batch row (0..3)
    float w0c[6], b0c;
#pragma unroll
    for (int k = 0; k < 6; ++k) w0c[k] = w0p[col0 * 6 + k];
    b0c = b0p[col0];
    const float b1c = b1p[mycol], b2c = b2p[mycol], b3c = b3p[mycol];

    // stage conv weights w1..w3 into CW as B-fragments
    {
        const float* wp[3] = { w1p, w2p, w3p };
        for (int i = tid; i < 6144; i += 512) {
            int ln = i & 63, ki = (i >> 6) & 3, cg = (i >> 8) & 7, L = i >> 11;
            f16x8 v = load8cvt(wp[L] + (cg * 16 + (ln & 15)) * 128 + ki * 32 + (ln >> 4) * 8);
            *(f16x8*)(CW + i * 8) = v;
        }
    }
    for (int i = tid; i < 2 * 16 * 128; i += 512) ((f16*)HL)[i] = (f16)0.f;

    // src(t=0) preload
    float sv[6];
    {
        const float2* sp = (const float2*)src + ((size_t)(bb0 + row0) * T_) * 3;
        float2 a = sp[0], b = sp[1], c2 = sp[2];
        sv[0] = a.x; sv[1] = a.y; sv[2] = b.x; sv[3] = b.y; sv[4] = c2.x; sv[5] = c2.y;
    }
    float c = 0.f, h = 0.f;
    __syncthreads();

    auto conv_layer = [&](const f16* Xin, f16* Xout, int L, float bc, float addv) {
        f16x8 af[4], bf[4];
#pragma unroll
        for (int ki = 0; ki < 4; ++ki) {
            af[ki] = lds_rd8(Xin, l16, ki * 64 + hi * 16);
            bf[ki] = *(const f16x8*)(CW + (((L * 8 + wid) * 4 + ki) << 9) + lane * 8);
        }
        f32x4 acc = { bc, bc, bc, bc };
#pragma unroll
        for (int ki = 0; ki < 4; ++ki)
            acc = __builtin_amdgcn_mfma_f32_16x16x32_f16(af[ki], bf[ki], acc, 0, 0, 0);
        lds_wr1(Xout, hi * 4, mycol, (f16)(gelu_f(acc[0]) + addv));
    };

    for (int t = 0; t < T_; ++t) {
        // --- P0: conv layer0 into XA; ys[t-1] flush; prefetches ---
        {
            float a = b0c;
#pragma unroll
            for (int k = 0; k < 6; ++k) a = fmaf(sv[k], w0c[k], a);
            lds_wr1(XA, row0 * 4, col0, (f16)gelu_f(a));
        }
        if (wid == 0 && t > 0) {
            f16x8 v = lds_rd8(HL[t & 1], (lane >> 4) * 4, (lane & 15) * 16);
            *(f16x8*)(ys + (size_t)(t - 1) * (B_ * H_) +
                      (size_t)(bb0 + (lane >> 4)) * H_ + (lane & 15) * 8) = v;
        }
        const float pv = posp[t * 128 + mycol];
        float svn[6];
        {
            const int tn = (t + 1 < T_) ? t + 1 : t;
            const float2* sp = (const float2*)src + ((size_t)(bb0 + row0) * T_ + tn) * 3;
            float2 a = sp[0], b = sp[1], c2 = sp[2];
            svn[0] = a.x; svn[1] = a.y; svn[2] = b.x; svn[3] = b.y; svn[4] = c2.x; svn[5] = c2.y;
        }
        __syncthreads();
        // --- P1..P3: conv layers 1..3 ---
        conv_layer(XA, XB, 0, b1c, 0.f);
        __syncthreads();
        conv_layer(XB, XA, 1, b2c, 0.f);
        __syncthreads();
        conv_layer(XA, XB, 2, b3c, pv);
        __syncthreads();
        // --- P4: lstm0 ---
        {
            f16x8 xa[4], ha[4];
#pragma unroll
            for (int ki = 0; ki < 4; ++ki) {
                xa[ki] = lds_rd8(XB, l16, ki * 64 + hi * 16);
                ha[ki] = lds_rd8(HL[t & 1], l16, ki * 64 + hi * 16);
            }
            f32x4 acc[4];
#pragma unroll
            for (int g = 0; g < 4; ++g) {
                f32x4 bv = { biasg[g], biasg[g], biasg[g], biasg[g] };
                acc[g] = bv;
            }
#pragma unroll
            for (int ki = 0; ki < 4; ++ki)
#pragma unroll
                for (int g = 0; g < 4; ++g)
                    acc[g] = __builtin_amdgcn_mfma_f32_16x16x32_f16(xa[ki], wih[g][ki], acc[g], 0, 0, 0);
#pragma unroll
            for (int ki = 0; ki < 4; ++ki)
#pragma unroll
                for (int g = 0; g < 4; ++g)
                    acc[g] = __builtin_amdgcn_mfma_f32_16x16x32_f16(ha[ki], whh[g][ki], acc[g], 0, 0, 0);
            float zi = acc[0][0], zf = acc[1][0], zg = acc[2][0], zo = acc[3][0];
            c = sig_f(zf) * c + sig_f(zi) * tanh_f(zg);
            h = sig_f(zo) * tanh_f(c);
            lds_wr1(HL[(t + 1) & 1], hi * 4, mycol, (f16)h);
        }
#pragma unroll
        for (int k = 0; k < 6; ++k) sv[k] = svn[k];
        __syncthreads();
    }
    // final ys[511] flush (h(511) lives in HL[512&1] = HL[0])
    if (wid == 0) {
        f16x8 v = lds_rd8(HL[0], (lane >> 4) * 4, (lane & 15) * 16);
        *(f16x8*)(ys + (size_t)(T_ - 1) * (B_ * H_) +
                  (size_t)(bb0 + (lane >> 4)) * H_ + (lane & 15) * 8) = v;
    }
}

// ---------------------------------------------------------------------------
// K2: LSTM layer 1 (reads ys from global, writes only final h). Unchanged
// from R2 (frozen for risk control; counters next round guide its fusion).
// ---------------------------------------------------------------------------
__global__ __launch_bounds__(512, 2) void lstm1_k(
    const f16* __restrict__ xb,
    const float* __restrict__ Wih, const float* __restrict__ Whh,
    const float* __restrict__ bih, const float* __restrict__ bhh,
    float* __restrict__ hfin)
{
    __shared__ f16 HL[2][16 * 128];
    const int tid = threadIdx.x;
    const int lane = tid & 63, wid = tid >> 6;
    const int l16 = lane & 15, hi = lane >> 4;
    const int bb0 = blockIdx.x * 4;

    f16x8 wih[4][4], whh[4][4];
    float bias[4];
#pragma unroll
    for (int g = 0; g < 4; ++g) {
        int n = g * 128 + wid * 16 + l16;
        bias[g] = bih[n] + bhh[n];
#pragma unroll
        for (int ki = 0; ki < 4; ++ki) {
            wih[g][ki] = load8cvt(Wih + n * 128 + ki * 32 + hi * 8);
            whh[g][ki] = load8cvt(Whh + n * 128 + ki * 32 + hi * 8);
        }
    }
    for (int i = tid; i < 2 * 16 * 128; i += 512) ((f16*)HL)[i] = (f16)0.f;

    const bool arow = (l16 & 3) == 0;
    const int brow = l16 >> 2;
    const f16* xbase = xb + (size_t)(bb0 + brow) * H_;
    const int mycol = wid * 16 + l16;
    float c = 0.f, h = 0.f;
    __syncthreads();

    f16x8 xa[4];
    const f16x8 zero8 = { 0, 0, 0, 0, 0, 0, 0, 0 };
#pragma unroll
    for (int ki = 0; ki < 4; ++ki)
        xa[ki] = arow ? *(const f16x8*)(xbase + ki * 32 + hi * 8) : zero8;

    for (int t = 0; t < T_; ++t) {
        const int tn = (t + 1 < T_) ? t + 1 : T_ - 1;
        const f16* xnp = xbase + (size_t)tn * (B_ * H_);
        f16x8 xn[4];
#pragma unroll
        for (int ki = 0; ki < 4; ++ki)
            xn[ki] = arow ? *(const f16x8*)(xnp + ki * 32 + hi * 8) : zero8;

        f16x8 ha[4];
#pragma unroll
        for (int ki = 0; ki < 4; ++ki)
            ha[ki] = lds_rd8(HL[t & 1], l16, ki * 64 + hi * 16);

        f32x4 acc[4];
#pragma unroll
        for (int g = 0; g < 4; ++g) {
            f32x4 bv = { bias[g], bias[g], bias[g], bias[g] };
            acc[g] = bv;
        }
#pragma unroll
        for (int ki = 0; ki < 4; ++ki)
#pragma unroll
            for (int g = 0; g < 4; ++g)
                acc[g] = __builtin_amdgcn_mfma_f32_16x16x32_f16(xa[ki], wih[g][ki], acc[g], 0, 0, 0);
#pragma unroll
        for (int ki = 0; ki < 4; ++ki)
#pragma unroll
            for (int g = 0; g < 4; ++g)
                acc[g] = __builtin_amdgcn_mfma_f32_16x16x32_f16(ha[ki], whh[g][ki], acc[g], 0, 0, 0);

        float zi = acc[0][0], zf = acc[1][0], zg = acc[2][0], zo = acc[3][0];
        c = sig_f(zf) * c + sig_f(zi) * tanh_f(zg);
        h = sig_f(zo) * tanh_f(c);
        lds_wr1(HL[(t + 1) & 1], hi * 4, mycol, (f16)h);

#pragma unroll
        for (int ki = 0; ki < 4; ++ki) xa[ki] = xn[ki];
        __syncthreads();
    }
    hfin[(size_t)(bb0 + hi) * H_ + mycol] = h;
}

// ---------------------------------------------------------------------------
// K3: head — LayerNorm + Linear(128->32) + GELU + Linear(32->8). 4 rows/block.
// ---------------------------------------------------------------------------
__global__ __launch_bounds__(256) void head_k(
    const float* __restrict__ hfin,
    const float* __restrict__ lng, const float* __restrict__ lnb,
    const float* __restrict__ hw1, const float* __restrict__ hb1,
    const float* __restrict__ hw2, const float* __restrict__ hb2,
    float* __restrict__ outp)
{
    __shared__ float HN[4][128];
    __shared__ float G[4][32];
    const int tid = threadIdx.x, lane = tid & 63, wid = tid >> 6;
    const int b = blockIdx.x * 4 + wid;
    float v0 = hfin[b * 128 + lane], v1 = hfin[b * 128 + 64 + lane];
    float s = v0 + v1;
#pragma unroll
    for (int m = 1; m < 64; m <<= 1) s += __shfl_xor(s, m);
    float mu = s * (1.f / 128.f);
    float d0 = v0 - mu, d1 = v1 - mu;
    float q = d0 * d0 + d1 * d1;
#pragma unroll
    for (int m = 1; m < 64; m <<= 1) q += __shfl_xor(q, m);
    float rs = rsqrtf(q * (1.f / 128.f) + 1e-5f);
    HN[wid][lane] = d0 * rs * lng[lane] + lnb[lane];
    HN[wid][64 + lane] = d1 * rs * lng[64 + lane] + lnb[64 + lane];
    __syncthreads();
    if (tid < 128) {
        int row = tid >> 5, o = tid & 31;
        float a = hb1[o];
#pragma unroll 4
        for (int k = 0; k < 128; ++k) a = fmaf(HN[row][k], hw1[o * 128 + k], a);
        G[row][o] = gelu_f(a);
    }
    __syncthreads();
    if (tid < 32) {
        int row = tid >> 3, oo = tid & 7;
        float a = hb2[oo];
#pragma unroll
        for (int k = 0; k < 32; ++k) a = fmaf(G[row][k], hw2[oo * 32 + k], a);
        outp[(size_t)(blockIdx.x * 4 + row) * 8 + oo] = a;
    }
}

extern "C" void kernel_launch(void* const* d_in, const int* in_sizes, int n_in,
                              void* d_out, int out_size, void* d_ws, size_t ws_size,
                              hipStream_t stream) {
    (void)in_sizes; (void)n_in; (void)out_size; (void)ws_size;
    const float* src  = (const float*)d_in[0];
    const float* w0   = (const float*)d_in[1];
    const float* b0   = (const float*)d_in[2];
    const float* w1   = (const float*)d_in[3];
    const float* b1   = (const float*)d_in[4];
    const float* w2   = (const float*)d_in[5];
    const float* b2   = (const float*)d_in[6];
    const float* w3   = (const float*)d_in[7];
    const float* b3   = (const float*)d_in[8];
    const float* pos  = (const float*)d_in[9];
    const float* Wih0 = (const float*)d_in[10];
    const float* Whh0 = (const float*)d_in[11];
    const float* bih0 = (const float*)d_in[12];
    const float* bhh0 = (const float*)d_in[13];
    const float* Wih1 = (const float*)d_in[14];
    const float* Whh1 = (const float*)d_in[15];
    const float* bih1 = (const float*)d_in[16];
    const float* bhh1 = (const float*)d_in[17];
    const float* lng  = (const float*)d_in[18];
    const float* lnb  = (const float*)d_in[19];
    const float* hw1  = (const float*)d_in[20];
    const float* hb1  = (const float*)d_in[21];
    const float* hw2  = (const float*)d_in[22];
    const float* hb2  = (const float*)d_in[23];
    float* outp = (float*)d_out;

    f16* ysbuf = (f16*)d_ws;                                 // (T,B,H) f16 = 128 MB
    float* hfin = (float*)((char*)d_ws + (size_t)134217728); // (B,H) f32

    fused_conv_lstm0_k<<<dim3(256), dim3(512), 0, stream>>>(
        src, w0, b0, w1, b1, w2, b2, w3, b3, pos,
        Wih0, Whh0, bih0, bhh0, ysbuf);
    lstm1_k<<<dim3(256), dim3(512), 0, stream>>>(
        ysbuf, Wih1, Whh1, bih1, bhh1, hfin);
    head_k<<<dim3(256), dim3(256), 0, stream>>>(
        hfin, lng, lnb, hw1, hb1, hw2, hb2, outp);
}